// Round 1
// baseline (2415.100 us; speedup 1.0000x reference)
//
#include <hip/hip_runtime.h>
#include <math.h>

// Problem dims
#define D 256
#define NEF 8192        // feature codebook
#define NEC 1024        // class codebook
#define NRF 16384       // feature rows (256 tokens x 64 batch)

// Output layout (flat float32): loss | quantized[257*64*3*256] | f_perp | c_perp | idx[257*64*3]
#define OUT_QBASE   1
#define OUT_FPERP   12632065
#define OUT_CPERP   12632066
#define OUT_IDXBASE 12632067

// LDS tile strides (floats). 68/132: multiples of 4 (16B-aligned b128 rows),
// chosen so compute-phase reads are broadcast / 2-way (free) on 32 banks.
#define XT_STRIDE 68
#define E_STRIDE  132
#define SXT_SIZE (64 * XT_STRIDE)   // 4352 floats = 17.0 KB
#define SE_SIZE  (64 * E_STRIDE)    // 8448 floats = 33.8 KB  (reused for top-k merge)

// Workspace offsets (bytes)
#define WS_COUNTS 0        // 8192 int
#define WS_LOSSF  32768    // 1 float
#define WS_CLS_S  32772    // 8*64*3 float  (class partial top-3 scores)
#define WS_CLS_I  38916    // 8*64*3 int    (class partial top-3 indices)
#define WS_E2F    49152    // 8192 float (16B aligned)
#define WS_E2C    81920    // 1024 float

// Lexicographic (score, idx) insert into a sorted 3-slot list.
// Matches jax.lax.top_k stable tie-breaking (equal score -> lower index wins).
__device__ __forceinline__ void insert3(float s, int idx, float* bs, int* bi) {
    bool lt2 = (s < bs[2]) || (s == bs[2] && idx < bi[2]);
    if (lt2) {
        bool lt1 = (s < bs[1]) || (s == bs[1] && idx < bi[1]);
        if (lt1) {
            bs[2] = bs[1]; bi[2] = bi[1];
            bool lt0 = (s < bs[0]) || (s == bs[0] && idx < bi[0]);
            if (lt0) { bs[1] = bs[0]; bi[1] = bi[0]; bs[0] = s; bi[0] = idx; }
            else     { bs[1] = s;     bi[1] = idx; }
        } else       { bs[2] = s;     bi[2] = idx; }
    }
}

// One block: 64 rows (xbase) vs nchunks*128 codes (emb). Per-thread local top-3
// per row kept in registers. tx=tid&15 (emb groups), ty=tid>>4 (row groups).
// Micro-tile: 4 rows x 8 embs (two quads at 4*tx and 64+4*tx -> 2-way-free b128s).
__device__ void vq_tile(const float* __restrict__ xbase, const float* __restrict__ emb,
                        const float* __restrict__ e2, int nchunks,
                        float bs[4][3], int bi[4][3],
                        float* sXT, float* sE, int tid, int tx, int ty)
{
#pragma unroll
    for (int r = 0; r < 4; ++r)
#pragma unroll
        for (int s = 0; s < 3; ++s) { bs[r][s] = 1e30f; bi[r][s] = 0x7FFFFFFF; }

    for (int c = 0; c < nchunks; ++c) {
        const int eblk = c * 128;
        const float4 e2a = *(const float4*)(e2 + eblk + 4 * tx);
        const float4 e2b = *(const float4*)(e2 + eblk + 64 + 4 * tx);
        float accA[4][4] = {};
        float accB[4][4] = {};
        for (int kt = 0; kt < 4; ++kt) {
            const int k0 = kt * 64;
            __syncthreads();   // protect LDS from overwrite while prior compute in flight
            // stage X tile transposed: [64 k][64 rows]
#pragma unroll
            for (int i = 0; i < 4; ++i) {
                int li  = tid + 256 * i;          // 0..1023
                int row = li >> 4;                // 0..63
                int k4  = (li & 15) << 2;         // 0..60
                float4 v = *(const float4*)(xbase + (size_t)row * D + k0 + k4);
                sXT[(k4 + 0) * XT_STRIDE + row] = v.x;
                sXT[(k4 + 1) * XT_STRIDE + row] = v.y;
                sXT[(k4 + 2) * XT_STRIDE + row] = v.z;
                sXT[(k4 + 3) * XT_STRIDE + row] = v.w;
            }
            // stage E tile transposed: [64 k][128 embs]
#pragma unroll
            for (int i = 0; i < 8; ++i) {
                int li = tid + 256 * i;           // 0..2047
                int e  = li >> 4;                 // 0..127
                int k4 = (li & 15) << 2;
                float4 v = *(const float4*)(emb + (size_t)(eblk + e) * D + k0 + k4);
                sE[(k4 + 0) * E_STRIDE + e] = v.x;
                sE[(k4 + 1) * E_STRIDE + e] = v.y;
                sE[(k4 + 2) * E_STRIDE + e] = v.z;
                sE[(k4 + 3) * E_STRIDE + e] = v.w;
            }
            __syncthreads();
#pragma unroll 4
            for (int k = 0; k < 64; ++k) {
                float4 av = *(const float4*)(sXT + k * XT_STRIDE + 4 * ty);
                float4 b0 = *(const float4*)(sE  + k * E_STRIDE  + 4 * tx);
                float4 b1 = *(const float4*)(sE  + k * E_STRIDE  + 64 + 4 * tx);
                float a[4] = {av.x, av.y, av.z, av.w};
                float p[4] = {b0.x, b0.y, b0.z, b0.w};
                float q[4] = {b1.x, b1.y, b1.z, b1.w};
#pragma unroll
                for (int r = 0; r < 4; ++r)
#pragma unroll
                    for (int j = 0; j < 4; ++j) {
                        accA[r][j] += a[r] * p[j];
                        accB[r][j] += a[r] * q[j];
                    }
            }
        }
        // score = ||e||^2 - 2 x.e  (row-constant ||x||^2 dropped; rank-identical)
        const int baseA = eblk + 4 * tx;
        const int baseB = baseA + 64;
        float e2av[4] = {e2a.x, e2a.y, e2a.z, e2a.w};
        float e2bv[4] = {e2b.x, e2b.y, e2b.z, e2b.w};
#pragma unroll
        for (int r = 0; r < 4; ++r) {
#pragma unroll
            for (int j = 0; j < 4; ++j)
                insert3(e2av[j] - 2.0f * accA[r][j], baseA + j, bs[r], bi[r]);
#pragma unroll
            for (int j = 0; j < 4; ++j)
                insert3(e2bv[j] - 2.0f * accB[r][j], baseB + j, bs[r], bi[r]);
        }
    }
}

// Merge 16 per-thread top-3 lists per row (via LDS, reusing sE). tid<64 holds result.
__device__ void merge_rows(float* sE, float bs[4][3], int bi[4][3],
                           int tid, int tx, int ty, float fb[3], int fi[3])
{
    float* cs = sE;
    int*   ci = (int*)sE + 3072;
    __syncthreads();   // all compute reads of sE done before overwrite
#pragma unroll
    for (int r = 0; r < 4; ++r) {
        int row = ty * 4 + r;
#pragma unroll
        for (int s = 0; s < 3; ++s) {
            cs[(row * 16 + tx) * 3 + s] = bs[r][s];
            ci[(row * 16 + tx) * 3 + s] = bi[r][s];
        }
    }
    __syncthreads();
    if (tid < 64) {
        fb[0] = fb[1] = fb[2] = 1e30f;
        fi[0] = fi[1] = fi[2] = 0x7FFFFFFF;
        for (int t = 0; t < 16; ++t)
            for (int s = 0; s < 3; ++s)
                insert3(cs[(tid * 16 + t) * 3 + s], ci[(tid * 16 + t) * 3 + s], fb, fi);
    }
}

__global__ void vq_norms(const float* __restrict__ femb, const float* __restrict__ cemb,
                         float* __restrict__ e2f, float* __restrict__ e2c)
{
    int wave = blockIdx.x * 4 + (threadIdx.x >> 6);
    int lane = threadIdx.x & 63;
    const float* src;
    float* dst;
    if (wave < NEF) { src = femb + (size_t)wave * D;         dst = e2f + wave; }
    else            { src = cemb + (size_t)(wave - NEF) * D; dst = e2c + (wave - NEF); }
    float s = 0.f;
#pragma unroll
    for (int i = 0; i < 4; ++i) { float v = src[lane + 64 * i]; s += v * v; }
#pragma unroll
    for (int off = 32; off > 0; off >>= 1) s += __shfl_down(s, off);
    if (lane == 0) *dst = s;
}

__global__ __launch_bounds__(256, 2)
void vq_main(const float* __restrict__ features, const float* __restrict__ femb,
             const float* __restrict__ cemb, const float* __restrict__ e2f,
             const float* __restrict__ e2c, float* __restrict__ out,
             int* __restrict__ counts_f, float* __restrict__ loss_f,
             float* __restrict__ cls_s, int* __restrict__ cls_i)
{
    __shared__ float sXT[SXT_SIZE];
    __shared__ float sE[SE_SIZE];
    const int tid = threadIdx.x;
    const int tx = tid & 15, ty = tid >> 4;
    const int blk = blockIdx.x;

    float bs[4][3]; int bi[4][3];
    float fb[3];    int fi[3];

    // ---- feature rows: 64 rows per block vs all 8192 feature codes
    const float* xbase = features + (size_t)(64 + blk * 64) * D;
    vq_tile(xbase, femb, e2f, 64, bs, bi, sXT, sE, tid, tx, ty);
    merge_rows(sE, bs, bi, tid, tx, ty, fb, fi);

    int* sfidx = (int*)sE + 6144;   // 192 final indices for gather phase
    if (tid < 64) {
        int grow = 64 + blk * 64 + tid;   // output row (class rows occupy 0..63)
#pragma unroll
        for (int s = 0; s < 3; ++s) {
            sfidx[tid * 3 + s] = fi[s];
            out[OUT_IDXBASE + (size_t)grow * 3 + s] = (float)(fi[s] + NEC);
            atomicAdd(&counts_f[fi[s]], 1);
        }
    }
    __syncthreads();

    // ---- gather emb[idx] -> quantized output + loss partial
    float lsum = 0.f;
    const int g = tid >> 4, l16 = tid & 15;
    for (int rs = g; rs < 192; rs += 16) {
        int row = rs / 3, slot = rs - row * 3;
        int idx = sfidx[rs];
        const float* ep = femb + (size_t)idx * D;
        const float* xp = xbase + (size_t)row * D;
        size_t ob = OUT_QBASE + ((size_t)(64 + blk * 64 + row) * 3 + slot) * D;
#pragma unroll
        for (int qq = 0; qq < 4; ++qq) {
            int kk = (qq * 16 + l16) * 4;
            float4 e = *(const float4*)(ep + kk);
            float4 x = *(const float4*)(xp + kk);
            float dx = e.x - x.x, dy = e.y - x.y, dz = e.z - x.z, dw = e.w - x.w;
            lsum += dx * dx + dy * dy + dz * dz + dw * dw;
            // scalar stores: quantized region starts at out+1 (4B-aligned only)
            out[ob + kk + 0] = e.x; out[ob + kk + 1] = e.y;
            out[ob + kk + 2] = e.z; out[ob + kk + 3] = e.w;
        }
    }
    float* red = sXT;
    red[tid] = lsum;
    __syncthreads();
    for (int s = 128; s > 0; s >>= 1) {
        if (tid < s) red[tid] += red[tid + s];
        __syncthreads();
    }
    if (tid == 0) atomicAdd(loss_f, red[0]);

    // ---- class slice: blocks 0..7 each handle 128 class codes vs rows 0..63
    if (blk < 8) {  // block-uniform branch: __syncthreads inside is safe
        vq_tile(features, cemb + (size_t)blk * 128 * D, e2c + blk * 128, 1,
                bs, bi, sXT, sE, tid, tx, ty);
        merge_rows(sE, bs, bi, tid, tx, ty, fb, fi);
        if (tid < 64) {
#pragma unroll
            for (int s = 0; s < 3; ++s) {
                cls_s[((size_t)blk * 64 + tid) * 3 + s] = fb[s];
                cls_i[((size_t)blk * 64 + tid) * 3 + s] = blk * 128 + fi[s];
            }
        }
    }
}

__global__ __launch_bounds__(256)
void vq_finalize(const float* __restrict__ features, const float* __restrict__ cemb,
                 float* __restrict__ out, const int* __restrict__ counts_f,
                 const float* __restrict__ loss_f, const float* __restrict__ cls_s,
                 const int* __restrict__ cls_i)
{
    __shared__ int ccount[NEC];
    __shared__ int cfidx[192];
    __shared__ float fred[256];
    __shared__ double dred[256];
    const int tid = threadIdx.x;

    for (int i = tid; i < NEC; i += 256) ccount[i] = 0;
    __syncthreads();

    // merge the 8 partial class top-3 lists per row
    if (tid < 64) {
        float fb[3] = {1e30f, 1e30f, 1e30f};
        int   fi[3] = {0x7FFFFFFF, 0x7FFFFFFF, 0x7FFFFFFF};
        for (int b = 0; b < 8; ++b)
            for (int s = 0; s < 3; ++s)
                insert3(cls_s[((size_t)b * 64 + tid) * 3 + s],
                        cls_i[((size_t)b * 64 + tid) * 3 + s], fb, fi);
        for (int s = 0; s < 3; ++s) {
            cfidx[tid * 3 + s] = fi[s];
            out[OUT_IDXBASE + (size_t)tid * 3 + s] = (float)fi[s];
            atomicAdd(&ccount[fi[s]], 1);
        }
    }
    __syncthreads();

    // class gather + loss
    float lsum = 0.f;
    const int g = tid >> 4, l16 = tid & 15;
    for (int rs = g; rs < 192; rs += 16) {
        int row = rs / 3, slot = rs - row * 3;
        int idx = cfidx[rs];
        const float* ep = cemb + (size_t)idx * D;
        const float* xp = features + (size_t)row * D;
        size_t ob = OUT_QBASE + ((size_t)row * 3 + slot) * D;
#pragma unroll
        for (int qq = 0; qq < 4; ++qq) {
            int kk = (qq * 16 + l16) * 4;
            float4 e = *(const float4*)(ep + kk);
            float4 x = *(const float4*)(xp + kk);
            float dx = e.x - x.x, dy = e.y - x.y, dz = e.z - x.z, dw = e.w - x.w;
            lsum += dx * dx + dy * dy + dz * dz + dw * dw;
            out[ob + kk + 0] = e.x; out[ob + kk + 1] = e.y;
            out[ob + kk + 2] = e.z; out[ob + kk + 3] = e.w;
        }
    }
    fred[tid] = lsum;
    __syncthreads();
    for (int s = 128; s > 0; s >>= 1) {
        if (tid < s) fred[tid] += fred[tid + s];
        __syncthreads();
    }
    float loss_c = fred[0];

    // feature perplexity (avg_probs = counts / n_rows; note it sums to 3 per reference)
    double acc = 0.0;
    for (int i = tid; i < NEF; i += 256) {
        double p = (double)counts_f[i] / 16384.0;
        acc += p * log(p + 1e-10);
    }
    dred[tid] = acc;
    __syncthreads();
    for (int s = 128; s > 0; s >>= 1) {
        if (tid < s) dred[tid] += dred[tid + s];
        __syncthreads();
    }
    double ent_f = -dred[0];
    __syncthreads();

    // class perplexity
    acc = 0.0;
    for (int i = tid; i < NEC; i += 256) {
        double p = (double)ccount[i] / 64.0;
        acc += p * log(p + 1e-10);
    }
    dred[tid] = acc;
    __syncthreads();
    for (int s = 128; s > 0; s >>= 1) {
        if (tid < s) dred[tid] += dred[tid + s];
        __syncthreads();
    }
    double ent_c = -dred[0];

    if (tid == 0) {
        out[OUT_FPERP] = (float)exp(ent_f);
        out[OUT_CPERP] = (float)exp(ent_c);
        float fl = *loss_f;
        // loss = 1.25 * (mean_c + mean_f): q_latent + 0.25*e_latent, values identical
        out[0] = 1.25f * (loss_c / 49152.0f + fl / 12582912.0f);
    }
}

extern "C" void kernel_launch(void* const* d_in, const int* in_sizes, int n_in,
                              void* d_out, int out_size, void* d_ws, size_t ws_size,
                              hipStream_t stream)
{
    const float* features = (const float*)d_in[0];  // [257*64, 256]
    const float* cemb     = (const float*)d_in[1];  // [1024, 256]
    const float* femb     = (const float*)d_in[2];  // [8192, 256]
    float* out = (float*)d_out;
    char*  ws  = (char*)d_ws;

    int*   counts_f = (int*)  (ws + WS_COUNTS);
    float* loss_f   = (float*)(ws + WS_LOSSF);
    float* cls_s    = (float*)(ws + WS_CLS_S);
    int*   cls_i    = (int*)  (ws + WS_CLS_I);
    float* e2f      = (float*)(ws + WS_E2F);
    float* e2c      = (float*)(ws + WS_E2C);

    // zero counts + loss accumulator (ws is poisoned 0xAA before every call)
    hipMemsetAsync(d_ws, 0, 32772, stream);
    vq_norms<<<2304, 256, 0, stream>>>(femb, cemb, e2f, e2c);
    vq_main<<<256, 256, 0, stream>>>(features, femb, cemb, e2f, e2c, out,
                                     counts_f, loss_f, cls_s, cls_i);
    vq_finalize<<<1, 256, 0, stream>>>(features, cemb, out, counts_f, loss_f,
                                       cls_s, cls_i);
}

// Round 2
// 1526.963 us; speedup vs baseline: 1.5816x; 1.5816x over previous
//
#include <hip/hip_runtime.h>
#include <math.h>

// Problem dims
#define D 256
#define NEF 8192        // feature codebook
#define NEC 1024        // class codebook

// Output layout (flat float32): loss | quantized[257*64*3*256] | f_perp | c_perp | idx[257*64*3]
#define OUT_QBASE   1
#define OUT_FPERP   12632065
#define OUT_CPERP   12632066
#define OUT_IDXBASE 12632067

// Row-major LDS tile stride (floats): 32 k + 4 pad. Staging b128 writes and
// compute b128 reads are bank-conflict-free with this stride (see analysis).
#define S_LD 36

// Partial top-3 scratch lives in the quantized output region (out+OUT_QBASE),
// which vq_gather rewrites afterwards (stream-ordered, safe). Float offsets:
#define PSC_OFF 0        // feature partial scores  [4 part][16384 row][3]
#define PIX_OFF 196608   // feature partial indices [4][16384][3] (int view)
#define CSC_OFF 393216   // class partial scores    [4 part][64 row][3]
#define CIX_OFF 393984   // class partial indices

// Workspace layout (bytes)
#define WS_CNTF  0       // 8192 int
#define WS_CNTC  32768   // 1024 int
#define WS_LOSSC 36864   // float
#define WS_LOSSF 36868   // float
#define WS_E2F   49152   // 8192 float
#define WS_E2C   81920   // 1024 float

// Lexicographic (score, idx) insert into a sorted 3-slot list.
// Matches jax.lax.top_k stable tie-breaking (equal score -> lower index wins).
__device__ __forceinline__ void insert3(float s, int idx, float* bs, int* bi) {
    bool lt2 = (s < bs[2]) || (s == bs[2] && idx < bi[2]);
    if (lt2) {
        bool lt1 = (s < bs[1]) || (s == bs[1] && idx < bi[1]);
        if (lt1) {
            bs[2] = bs[1]; bi[2] = bi[1];
            bool lt0 = (s < bs[0]) || (s == bs[0] && idx < bi[0]);
            if (lt0) { bs[1] = bs[0]; bi[1] = bi[0]; bs[0] = s; bi[0] = idx; }
            else     { bs[1] = s;     bi[1] = idx; }
        } else       { bs[2] = s;     bi[2] = idx; }
    }
}

// ---- codebook squared norms (float4 per lane, one wave per code row)
__global__ __launch_bounds__(256)
void vq_norms(const float* __restrict__ femb, const float* __restrict__ cemb,
              float* __restrict__ e2f, float* __restrict__ e2c)
{
    int wave = blockIdx.x * 4 + (threadIdx.x >> 6);
    int lane = threadIdx.x & 63;
    const float* src;
    float* dst;
    if (wave < NEF) { src = femb + (size_t)wave * D;         dst = e2f + wave; }
    else            { src = cemb + (size_t)(wave - NEF) * D; dst = e2c + (wave - NEF); }
    float4 v = *(const float4*)(src + lane * 4);
    float s = v.x * v.x + v.y * v.y + v.z * v.z + v.w * v.w;
#pragma unroll
    for (int off = 32; off > 0; off >>= 1) s += __shfl_down(s, off);
    if (lane == 0) *dst = s;
}

// ---- main distance + partial top-3 kernel
// Feature blocks (0..1023): rt = blk>>2 -> rows [64+rt*64, +64); pt = blk&3 ->
// codes [pt*2048, +2048). Class blocks (1024..1027): rows 0..63, codes [p*256,+256).
// Thread (tx=tid&15, ty=tid>>4) owns rows {ty+16i} x embs {tx+16j} (4x8 micro).
__global__ __launch_bounds__(256, 4)
void vq_partial(const float* __restrict__ features, const float* __restrict__ femb,
                const float* __restrict__ cemb, const float* __restrict__ e2f,
                const float* __restrict__ e2c, float* __restrict__ out)
{
    __shared__ float sm[(64 + 128) * S_LD];   // 6912 floats = 27.6 KB
    float* sX = sm;                 // [64 rows][S_LD]
    float* sE = sm + 64 * S_LD;     // [128 embs][S_LD]
    const int tid = threadIdx.x, tx = tid & 15, ty = tid >> 4;
    const int blk = blockIdx.x;
    const bool is_class = blk >= 1024;

    const float* xbase;
    const float* emb;
    const float* e2;
    int nchunks, eoff;
    if (is_class) {
        int p = blk - 1024;
        xbase = features;                       // rows 0..63 (class token)
        emb   = cemb + (size_t)p * 256 * D;
        e2    = e2c + p * 256;
        nchunks = 2;
        eoff = p * 256;
    } else {
        int rt = blk >> 2, pt = blk & 3;
        xbase = features + (size_t)(64 + rt * 64) * D;
        emb   = femb + (size_t)pt * 2048 * D;
        e2    = e2f + pt * 2048;
        nchunks = 16;
        eoff = pt * 2048;
    }

    float bs[4][3]; int bi[4][3];
#pragma unroll
    for (int i = 0; i < 4; ++i)
#pragma unroll
        for (int s = 0; s < 3; ++s) { bs[i][s] = 1e30f; bi[i][s] = 0x7FFFFFFF; }

    for (int c = 0; c < nchunks; ++c) {
        const float* ec = emb + (size_t)c * 128 * D;
        float acc[4][8] = {};
        for (int kt = 0; kt < 8; ++kt) {
            const int k0 = kt * 32;
            __syncthreads();   // prior compute reads done before overwrite
            // stage X: 64 rows x 32 k, b128 row-major writes (conflict-free:
            // 8-lane phase = 1 row x 8 k-quads -> banks 4(row+t) all distinct)
#pragma unroll
            for (int i = 0; i < 2; ++i) {
                int li = tid + 256 * i;
                int row = li >> 3, kq = (li & 7) << 2;
                *(float4*)(sX + row * S_LD + kq) =
                    *(const float4*)(xbase + (size_t)row * D + k0 + kq);
            }
            // stage E: 128 embs x 32 k
#pragma unroll
            for (int i = 0; i < 4; ++i) {
                int li = tid + 256 * i;
                int e = li >> 3, kq = (li & 7) << 2;
                *(float4*)(sE + e * S_LD + kq) =
                    *(const float4*)(ec + (size_t)e * D + k0 + kq);
            }
            __syncthreads();
#pragma unroll 2
            for (int k4 = 0; k4 < 8; ++k4) {
                const int kk = k4 * 4;
                float4 xf[4], ef[8];
#pragma unroll
                for (int i = 0; i < 4; ++i)   // broadcast across tx: free
                    xf[i] = *(const float4*)(sX + (ty + 16 * i) * S_LD + kk);
#pragma unroll
                for (int j = 0; j < 8; ++j)   // banks 4*tx: conflict-free
                    ef[j] = *(const float4*)(sE + (tx + 16 * j) * S_LD + kk);
#pragma unroll
                for (int i = 0; i < 4; ++i)
#pragma unroll
                    for (int j = 0; j < 8; ++j) {
                        float a = acc[i][j];
                        a = fmaf(xf[i].x, ef[j].x, a);
                        a = fmaf(xf[i].y, ef[j].y, a);
                        a = fmaf(xf[i].z, ef[j].z, a);
                        a = fmaf(xf[i].w, ef[j].w, a);
                        acc[i][j] = a;
                    }
            }
        }
        // score = ||e||^2 - 2 x.e (row-constant ||x||^2 dropped, rank-identical;
        // fmaf(-2,acc,e2) == e2 - 2*acc exactly: 2*acc is exact, one rounding)
#pragma unroll
        for (int j = 0; j < 8; ++j) {
            int el = c * 128 + tx + 16 * j;
            float e2v = e2[el];
#pragma unroll
            for (int i = 0; i < 4; ++i)
                insert3(fmaf(-2.0f, acc[i][j], e2v), el, bs[i], bi[i]);
        }
    }

    // merge the 16 tx-partials per row through LDS (reuse sm)
    __syncthreads();
    float* cs = sm;                 // 3072 floats
    int*   ci = (int*)sm + 3072;    // 3072 ints
#pragma unroll
    for (int i = 0; i < 4; ++i) {
        int row = ty + 16 * i;
#pragma unroll
        for (int s = 0; s < 3; ++s) {
            cs[(row * 16 + tx) * 3 + s] = bs[i][s];
            ci[(row * 16 + tx) * 3 + s] = bi[i][s];
        }
    }
    __syncthreads();
    if (tid < 64) {
        float fb[3] = {1e30f, 1e30f, 1e30f};
        int   fi[3] = {0x7FFFFFFF, 0x7FFFFFFF, 0x7FFFFFFF};
        for (int t = 0; t < 16; ++t)
            for (int s = 0; s < 3; ++s)
                insert3(cs[(tid * 16 + t) * 3 + s], ci[(tid * 16 + t) * 3 + s], fb, fi);
        float* base = out + OUT_QBASE;
        int*  ibase = (int*)base;
        if (is_class) {
            int p = blk - 1024;
#pragma unroll
            for (int s = 0; s < 3; ++s) {
                base [CSC_OFF + (p * 64 + tid) * 3 + s] = fb[s];
                ibase[CIX_OFF + (p * 64 + tid) * 3 + s] = fi[s] + eoff;
            }
        } else {
            int rt = blk >> 2, pt = blk & 3;
            int gr = rt * 64 + tid;   // feature row 0..16383
#pragma unroll
            for (int s = 0; s < 3; ++s) {
                base [PSC_OFF + (size_t)pt * 49152 + (size_t)gr * 3 + s] = fb[s];
                ibase[PIX_OFF + (size_t)pt * 49152 + (size_t)gr * 3 + s] = fi[s] + eoff;
            }
        }
    }
}

// ---- merge the 4 emb-part partials per row, write final indices + counts
__global__ __launch_bounds__(256)
void vq_merge(float* __restrict__ out, int* __restrict__ counts_f,
              int* __restrict__ counts_c)
{
    const int tid = threadIdx.x, blk = blockIdx.x;
    const float* base = out + OUT_QBASE;
    const int*  ibase = (const int*)base;
    if (blk < 64) {
        int r = blk * 256 + tid;    // feature row
        float fb[3] = {1e30f, 1e30f, 1e30f};
        int   fi[3] = {0x7FFFFFFF, 0x7FFFFFFF, 0x7FFFFFFF};
        for (int p = 0; p < 4; ++p)
            for (int s = 0; s < 3; ++s)
                insert3(base [PSC_OFF + (size_t)p * 49152 + (size_t)r * 3 + s],
                        ibase[PIX_OFF + (size_t)p * 49152 + (size_t)r * 3 + s], fb, fi);
#pragma unroll
        for (int s = 0; s < 3; ++s) {
            out[OUT_IDXBASE + (size_t)(64 + r) * 3 + s] = (float)(fi[s] + NEC);
            atomicAdd(&counts_f[fi[s]], 1);
        }
    } else if (tid < 64) {
        int r = tid;                // class row
        float fb[3] = {1e30f, 1e30f, 1e30f};
        int   fi[3] = {0x7FFFFFFF, 0x7FFFFFFF, 0x7FFFFFFF};
        for (int p = 0; p < 4; ++p)
            for (int s = 0; s < 3; ++s)
                insert3(base [CSC_OFF + (p * 64 + r) * 3 + s],
                        ibase[CIX_OFF + (p * 64 + r) * 3 + s], fb, fi);
#pragma unroll
        for (int s = 0; s < 3; ++s) {
            out[OUT_IDXBASE + (size_t)r * 3 + s] = (float)fi[s];
            atomicAdd(&counts_c[fi[s]], 1);
        }
    }
}

// ---- gather emb[idx] -> quantized output, accumulate losses
// Block covers 4 (row,slot) pairs; slot boundary class/feature at block 48.
__global__ __launch_bounds__(256)
void vq_gather(const float* __restrict__ features, const float* __restrict__ femb,
               const float* __restrict__ cemb, float* __restrict__ out,
               float* __restrict__ loss_c, float* __restrict__ loss_f)
{
    const int tid = threadIdx.x;
    const int s = blockIdx.x * 4 + (tid >> 6);   // slot in [0, 49344)
    const int lane = tid & 63;
    const int row = s / 3;                        // global token-row 0..16447
    const int idx = (int)out[OUT_IDXBASE + s];
    const float* xp = features + (size_t)row * D;
    const float* ep = (row < 64) ? cemb + (size_t)idx * D
                                 : femb + (size_t)(idx - NEC) * D;
    const int koff = lane * 4;
    float4 e = *(const float4*)(ep + koff);
    float4 x = *(const float4*)(xp + koff);
    float dx = e.x - x.x, dy = e.y - x.y, dz = e.z - x.z, dw = e.w - x.w;
    float lsum = dx * dx + dy * dy + dz * dz + dw * dw;
    size_t ob = OUT_QBASE + (size_t)s * D + koff;   // base misaligned by 1 -> b32 stores
    out[ob + 0] = e.x; out[ob + 1] = e.y; out[ob + 2] = e.z; out[ob + 3] = e.w;
#pragma unroll
    for (int off = 32; off > 0; off >>= 1) lsum += __shfl_down(lsum, off);
    __shared__ float wl[4];
    if (lane == 0) wl[tid >> 6] = lsum;
    __syncthreads();
    if (tid == 0) {
        float t = wl[0] + wl[1] + wl[2] + wl[3];
        atomicAdd(blockIdx.x < 48 ? loss_c : loss_f, t);
    }
}

// ---- scalar epilogue: perplexities + loss
__global__ __launch_bounds__(256)
void vq_finalize(float* __restrict__ out, const int* __restrict__ counts_f,
                 const int* __restrict__ counts_c, const float* __restrict__ loss_c,
                 const float* __restrict__ loss_f)
{
    __shared__ double dred[256];
    const int tid = threadIdx.x;
    double acc = 0.0;
    for (int i = tid; i < NEF; i += 256) {
        double p = (double)counts_f[i] / 16384.0;
        acc += p * log(p + 1e-10);
    }
    dred[tid] = acc;
    __syncthreads();
    for (int st = 128; st > 0; st >>= 1) {
        if (tid < st) dred[tid] += dred[tid + st];
        __syncthreads();
    }
    double ent_f = -dred[0];
    __syncthreads();
    acc = 0.0;
    for (int i = tid; i < NEC; i += 256) {
        double p = (double)counts_c[i] / 64.0;
        acc += p * log(p + 1e-10);
    }
    dred[tid] = acc;
    __syncthreads();
    for (int st = 128; st > 0; st >>= 1) {
        if (tid < st) dred[tid] += dred[tid + st];
        __syncthreads();
    }
    double ent_c = -dred[0];
    if (tid == 0) {
        out[OUT_FPERP] = (float)exp(ent_f);
        out[OUT_CPERP] = (float)exp(ent_c);
        out[0] = 1.25f * (*loss_c / 49152.0f + *loss_f / 12582912.0f);
    }
}

extern "C" void kernel_launch(void* const* d_in, const int* in_sizes, int n_in,
                              void* d_out, int out_size, void* d_ws, size_t ws_size,
                              hipStream_t stream)
{
    const float* features = (const float*)d_in[0];  // [257*64, 256]
    const float* cemb     = (const float*)d_in[1];  // [1024, 256]
    const float* femb     = (const float*)d_in[2];  // [8192, 256]
    float* out = (float*)d_out;
    char*  ws  = (char*)d_ws;

    int*   counts_f = (int*)  (ws + WS_CNTF);
    int*   counts_c = (int*)  (ws + WS_CNTC);
    float* loss_c   = (float*)(ws + WS_LOSSC);
    float* loss_f   = (float*)(ws + WS_LOSSF);
    float* e2f      = (float*)(ws + WS_E2F);
    float* e2c      = (float*)(ws + WS_E2C);

    // zero counts + loss accumulators (ws is poisoned 0xAA before every call)
    hipMemsetAsync(d_ws, 0, 36872, stream);
    vq_norms<<<2304, 256, 0, stream>>>(femb, cemb, e2f, e2c);
    vq_partial<<<1028, 256, 0, stream>>>(features, femb, cemb, e2f, e2c, out);
    vq_merge<<<65, 256, 0, stream>>>(out, counts_f, counts_c);
    vq_gather<<<12336, 256, 0, stream>>>(features, femb, cemb, out, loss_c, loss_f);
    vq_finalize<<<1, 256, 0, stream>>>(out, counts_f, counts_c, loss_c, loss_f);
}

// Round 3
// 1329.297 us; speedup vs baseline: 1.8168x; 1.1487x over previous
//
#include <hip/hip_runtime.h>
#include <math.h>

// Problem dims
#define D 256
#define NEF 8192        // feature codebook
#define NEC 1024        // class codebook

// Output layout (flat float32): loss | quantized[257*64*3*256] | f_perp | c_perp | idx[257*64*3]
#define OUT_QBASE   1
#define OUT_FPERP   12632065
#define OUT_CPERP   12632066
#define OUT_IDXBASE 12632067

// Row-major LDS tile stride (floats): 32 k + 4 pad. Staging b128 writes and
// compute b128 reads are bank-conflict-free with this stride (verified R2:
// SQ_LDS_BANK_CONFLICT 1.77e8 -> 2.9e6).
#define S_LD 36

// Partial top-3 scratch lives in the quantized output region (out+OUT_QBASE),
// which vq_gather rewrites afterwards (stream-ordered, safe). Float offsets:
#define PSC_OFF 0        // feature partial scores  [4 part][16384 row][3]
#define PIX_OFF 196608   // feature partial indices [4][16384][3] (int view)
#define CSC_OFF 393216   // class partial scores    [4 part][64 row][3]
#define CIX_OFF 393984   // class partial indices

// Workspace layout (bytes)
#define WS_CNTF  0       // 8192 int
#define WS_CNTC  32768   // 1024 int
#define WS_LOSSC 36864   // float
#define WS_LOSSF 36868   // float
#define WS_E2F   49152   // 8192 float
#define WS_E2C   81920   // 1024 float

// Lexicographic (score, idx) insert into a sorted 3-slot list.
// Matches jax.lax.top_k stable tie-breaking (equal score -> lower index wins).
__device__ __forceinline__ void insert3(float s, int idx, float* bs, int* bi) {
    bool lt2 = (s < bs[2]) || (s == bs[2] && idx < bi[2]);
    if (lt2) {
        bool lt1 = (s < bs[1]) || (s == bs[1] && idx < bi[1]);
        if (lt1) {
            bs[2] = bs[1]; bi[2] = bi[1];
            bool lt0 = (s < bs[0]) || (s == bs[0] && idx < bi[0]);
            if (lt0) { bs[1] = bs[0]; bi[1] = bi[0]; bs[0] = s; bi[0] = idx; }
            else     { bs[1] = s;     bi[1] = idx; }
        } else       { bs[2] = s;     bi[2] = idx; }
    }
}

// ---- codebook squared norms (float4 per lane, one wave per code row)
__global__ __launch_bounds__(256)
void vq_norms(const float* __restrict__ femb, const float* __restrict__ cemb,
              float* __restrict__ e2f, float* __restrict__ e2c)
{
    int wave = blockIdx.x * 4 + (threadIdx.x >> 6);
    int lane = threadIdx.x & 63;
    const float* src;
    float* dst;
    if (wave < NEF) { src = femb + (size_t)wave * D;         dst = e2f + wave; }
    else            { src = cemb + (size_t)(wave - NEF) * D; dst = e2c + (wave - NEF); }
    float4 v = *(const float4*)(src + lane * 4);
    float s = v.x * v.x + v.y * v.y + v.z * v.z + v.w * v.w;
#pragma unroll
    for (int off = 32; off > 0; off >>= 1) s += __shfl_down(s, off);
    if (lane == 0) *dst = s;
}

// ---- main distance + partial top-3 kernel
// Feature blocks (0..1023): rt = blk>>2 -> rows [64+rt*64, +64); pt = blk&3 ->
// codes [pt*2048, +2048). Class blocks (1024..1027): rows 0..63, codes [p*256,+256).
// Thread (tx=tid&15, ty=tid>>4) owns rows {ty+16i} x embs {tx+16j} (4x8 micro).
// R3: inner loop restructured so peak live VGPRs ~90 (acc32+xf16+ef16+bases) --
// R2's unroll-2 blew the 128-VGPR cap and the compiler spilled acc to AGPRs
// (VGPR_Count=64, ~1.5 non-FMA VALU per FMA = v_accvgpr traffic).
__global__ __launch_bounds__(256, 4)
void vq_partial(const float* __restrict__ features, const float* __restrict__ femb,
                const float* __restrict__ cemb, const float* __restrict__ e2f,
                const float* __restrict__ e2c, float* __restrict__ out)
{
    __shared__ float sm[(64 + 128) * S_LD];   // 6912 floats = 27.6 KB
    float* sX = sm;                 // [64 rows][S_LD]
    float* sE = sm + 64 * S_LD;     // [128 embs][S_LD]
    const int tid = threadIdx.x, tx = tid & 15, ty = tid >> 4;
    const int blk = blockIdx.x;
    const bool is_class = blk >= 1024;

    const float* xbase;
    const float* emb;
    const float* e2;
    int nchunks, eoff;
    if (is_class) {
        int p = blk - 1024;
        xbase = features;                       // rows 0..63 (class token)
        emb   = cemb + (size_t)p * 256 * D;
        e2    = e2c + p * 256;
        nchunks = 2;
        eoff = p * 256;
    } else {
        int rt = blk >> 2, pt = blk & 3;
        xbase = features + (size_t)(64 + rt * 64) * D;
        emb   = femb + (size_t)pt * 2048 * D;
        e2    = e2f + pt * 2048;
        nchunks = 16;
        eoff = pt * 2048;
    }

    float bs[4][3]; int bi[4][3];
#pragma unroll
    for (int i = 0; i < 4; ++i)
#pragma unroll
        for (int s = 0; s < 3; ++s) { bs[i][s] = 1e30f; bi[i][s] = 0x7FFFFFFF; }

    for (int c = 0; c < nchunks; ++c) {
        const float* ec = emb + (size_t)c * 128 * D;
        float acc[4][8] = {};
        for (int kt = 0; kt < 8; ++kt) {
            const int k0 = kt * 32;
            __syncthreads();   // prior compute reads done before overwrite
            // stage X: 64 rows x 32 k, b128 row-major writes (conflict-free:
            // 8-lane phase = 1 row x 8 k-quads -> banks 4(row+t) all distinct)
#pragma unroll
            for (int i = 0; i < 2; ++i) {
                int li = tid + 256 * i;
                int row = li >> 3, kq = (li & 7) << 2;
                *(float4*)(sX + row * S_LD + kq) =
                    *(const float4*)(xbase + (size_t)row * D + k0 + kq);
            }
            // stage E: 128 embs x 32 k
#pragma unroll
            for (int i = 0; i < 4; ++i) {
                int li = tid + 256 * i;
                int e = li >> 3, kq = (li & 7) << 2;
                *(float4*)(sE + e * S_LD + kq) =
                    *(const float4*)(ec + (size_t)e * D + k0 + kq);
            }
            __syncthreads();
            // compute: 8 k-quads; emb fragments processed in two halves of 4
            // to keep live set = acc(32) + xf(16) + ef(16) + bases < 128 VGPRs
#pragma unroll 1
            for (int k4 = 0; k4 < 8; ++k4) {
                const int kk = k4 * 4;
                float4 xf[4];
#pragma unroll
                for (int i = 0; i < 4; ++i)   // broadcast across tx: free
                    xf[i] = *(const float4*)(sX + (ty + 16 * i) * S_LD + kk);
#pragma unroll
                for (int jh = 0; jh < 2; ++jh) {
                    float4 ef[4];
#pragma unroll
                    for (int j4 = 0; j4 < 4; ++j4)   // banks 4*tx: conflict-free
                        ef[j4] = *(const float4*)(sE + (tx + 16 * (jh * 4 + j4)) * S_LD + kk);
#pragma unroll
                    for (int i = 0; i < 4; ++i)
#pragma unroll
                        for (int j4 = 0; j4 < 4; ++j4) {
                            float a = acc[i][jh * 4 + j4];
                            a = fmaf(xf[i].x, ef[j4].x, a);
                            a = fmaf(xf[i].y, ef[j4].y, a);
                            a = fmaf(xf[i].z, ef[j4].z, a);
                            a = fmaf(xf[i].w, ef[j4].w, a);
                            acc[i][jh * 4 + j4] = a;
                        }
                }
            }
        }
        // score = ||e||^2 - 2 x.e (row-constant ||x||^2 dropped, rank-identical;
        // fmaf(-2,acc,e2) == e2 - 2*acc exactly: 2*acc is exact, one rounding)
#pragma unroll
        for (int j = 0; j < 8; ++j) {
            int el = c * 128 + tx + 16 * j;
            float e2v = e2[el];
#pragma unroll
            for (int i = 0; i < 4; ++i)
                insert3(fmaf(-2.0f, acc[i][j], e2v), el, bs[i], bi[i]);
        }
    }

    // merge the 16 tx-partials per row through LDS (reuse sm)
    __syncthreads();
    float* cs = sm;                 // 3072 floats
    int*   ci = (int*)sm + 3072;    // 3072 ints
#pragma unroll
    for (int i = 0; i < 4; ++i) {
        int row = ty + 16 * i;
#pragma unroll
        for (int s = 0; s < 3; ++s) {
            cs[(row * 16 + tx) * 3 + s] = bs[i][s];
            ci[(row * 16 + tx) * 3 + s] = bi[i][s];
        }
    }
    __syncthreads();
    if (tid < 64) {
        float fb[3] = {1e30f, 1e30f, 1e30f};
        int   fi[3] = {0x7FFFFFFF, 0x7FFFFFFF, 0x7FFFFFFF};
        for (int t = 0; t < 16; ++t)
            for (int s = 0; s < 3; ++s)
                insert3(cs[(tid * 16 + t) * 3 + s], ci[(tid * 16 + t) * 3 + s], fb, fi);
        float* base = out + OUT_QBASE;
        int*  ibase = (int*)base;
        if (is_class) {
            int p = blk - 1024;
#pragma unroll
            for (int s = 0; s < 3; ++s) {
                base [CSC_OFF + (p * 64 + tid) * 3 + s] = fb[s];
                ibase[CIX_OFF + (p * 64 + tid) * 3 + s] = fi[s] + eoff;
            }
        } else {
            int rt = blk >> 2, pt = blk & 3;
            int gr = rt * 64 + tid;   // feature row 0..16383
#pragma unroll
            for (int s = 0; s < 3; ++s) {
                base [PSC_OFF + (size_t)pt * 49152 + (size_t)gr * 3 + s] = fb[s];
                ibase[PIX_OFF + (size_t)pt * 49152 + (size_t)gr * 3 + s] = fi[s] + eoff;
            }
        }
    }
}

// ---- merge the 4 emb-part partials per row, write final indices + counts
__global__ __launch_bounds__(256)
void vq_merge(float* __restrict__ out, int* __restrict__ counts_f,
              int* __restrict__ counts_c)
{
    const int tid = threadIdx.x, blk = blockIdx.x;
    const float* base = out + OUT_QBASE;
    const int*  ibase = (const int*)base;
    if (blk < 64) {
        int r = blk * 256 + tid;    // feature row
        float fb[3] = {1e30f, 1e30f, 1e30f};
        int   fi[3] = {0x7FFFFFFF, 0x7FFFFFFF, 0x7FFFFFFF};
        for (int p = 0; p < 4; ++p)
            for (int s = 0; s < 3; ++s)
                insert3(base [PSC_OFF + (size_t)p * 49152 + (size_t)r * 3 + s],
                        ibase[PIX_OFF + (size_t)p * 49152 + (size_t)r * 3 + s], fb, fi);
#pragma unroll
        for (int s = 0; s < 3; ++s) {
            out[OUT_IDXBASE + (size_t)(64 + r) * 3 + s] = (float)(fi[s] + NEC);
            atomicAdd(&counts_f[fi[s]], 1);
        }
    } else if (tid < 64) {
        int r = tid;                // class row
        float fb[3] = {1e30f, 1e30f, 1e30f};
        int   fi[3] = {0x7FFFFFFF, 0x7FFFFFFF, 0x7FFFFFFF};
        for (int p = 0; p < 4; ++p)
            for (int s = 0; s < 3; ++s)
                insert3(base [CSC_OFF + (p * 64 + r) * 3 + s],
                        ibase[CIX_OFF + (p * 64 + r) * 3 + s], fb, fi);
#pragma unroll
        for (int s = 0; s < 3; ++s) {
            out[OUT_IDXBASE + (size_t)r * 3 + s] = (float)fi[s];
            atomicAdd(&counts_c[fi[s]], 1);
        }
    }
}

// ---- gather emb[idx] -> quantized output, accumulate losses
// Block covers 4 (row,slot) pairs; slot boundary class/feature at block 48.
__global__ __launch_bounds__(256)
void vq_gather(const float* __restrict__ features, const float* __restrict__ femb,
               const float* __restrict__ cemb, float* __restrict__ out,
               float* __restrict__ loss_c, float* __restrict__ loss_f)
{
    const int tid = threadIdx.x;
    const int s = blockIdx.x * 4 + (tid >> 6);   // slot in [0, 49344)
    const int lane = tid & 63;
    const int row = s / 3;                        // global token-row 0..16447
    const int idx = (int)out[OUT_IDXBASE + s];
    const float* xp = features + (size_t)row * D;
    const float* ep = (row < 64) ? cemb + (size_t)idx * D
                                 : femb + (size_t)(idx - NEC) * D;
    const int koff = lane * 4;
    float4 e = *(const float4*)(ep + koff);
    float4 x = *(const float4*)(xp + koff);
    float dx = e.x - x.x, dy = e.y - x.y, dz = e.z - x.z, dw = e.w - x.w;
    float lsum = dx * dx + dy * dy + dz * dz + dw * dw;
    size_t ob = OUT_QBASE + (size_t)s * D + koff;   // base misaligned by 1 -> b32 stores
    out[ob + 0] = e.x; out[ob + 1] = e.y; out[ob + 2] = e.z; out[ob + 3] = e.w;
#pragma unroll
    for (int off = 32; off > 0; off >>= 1) lsum += __shfl_down(lsum, off);
    __shared__ float wl[4];
    if (lane == 0) wl[tid >> 6] = lsum;
    __syncthreads();
    if (tid == 0) {
        float t = wl[0] + wl[1] + wl[2] + wl[3];
        atomicAdd(blockIdx.x < 48 ? loss_c : loss_f, t);
    }
}

// ---- scalar epilogue: perplexities + loss
__global__ __launch_bounds__(256)
void vq_finalize(float* __restrict__ out, const int* __restrict__ counts_f,
                 const int* __restrict__ counts_c, const float* __restrict__ loss_c,
                 const float* __restrict__ loss_f)
{
    __shared__ double dred[256];
    const int tid = threadIdx.x;
    double acc = 0.0;
    for (int i = tid; i < NEF; i += 256) {
        double p = (double)counts_f[i] / 16384.0;
        acc += p * log(p + 1e-10);
    }
    dred[tid] = acc;
    __syncthreads();
    for (int st = 128; st > 0; st >>= 1) {
        if (tid < st) dred[tid] += dred[tid + st];
        __syncthreads();
    }
    double ent_f = -dred[0];
    __syncthreads();
    acc = 0.0;
    for (int i = tid; i < NEC; i += 256) {
        double p = (double)counts_c[i] / 64.0;
        acc += p * log(p + 1e-10);
    }
    dred[tid] = acc;
    __syncthreads();
    for (int st = 128; st > 0; st >>= 1) {
        if (tid < st) dred[tid] += dred[tid + st];
        __syncthreads();
    }
    double ent_c = -dred[0];
    if (tid == 0) {
        out[OUT_FPERP] = (float)exp(ent_f);
        out[OUT_CPERP] = (float)exp(ent_c);
        out[0] = 1.25f * (*loss_c / 49152.0f + *loss_f / 12582912.0f);
    }
}

extern "C" void kernel_launch(void* const* d_in, const int* in_sizes, int n_in,
                              void* d_out, int out_size, void* d_ws, size_t ws_size,
                              hipStream_t stream)
{
    const float* features = (const float*)d_in[0];  // [257*64, 256]
    const float* cemb     = (const float*)d_in[1];  // [1024, 256]
    const float* femb     = (const float*)d_in[2];  // [8192, 256]
    float* out = (float*)d_out;
    char*  ws  = (char*)d_ws;

    int*   counts_f = (int*)  (ws + WS_CNTF);
    int*   counts_c = (int*)  (ws + WS_CNTC);
    float* loss_c   = (float*)(ws + WS_LOSSC);
    float* loss_f   = (float*)(ws + WS_LOSSF);
    float* e2f      = (float*)(ws + WS_E2F);
    float* e2c      = (float*)(ws + WS_E2C);

    // zero counts + loss accumulators (ws is poisoned 0xAA before every call)
    hipMemsetAsync(d_ws, 0, 36872, stream);
    vq_norms<<<2304, 256, 0, stream>>>(femb, cemb, e2f, e2c);
    vq_partial<<<1028, 256, 0, stream>>>(features, femb, cemb, e2f, e2c, out);
    vq_merge<<<65, 256, 0, stream>>>(out, counts_f, counts_c);
    vq_gather<<<12336, 256, 0, stream>>>(features, femb, cemb, out, loss_c, loss_f);
    vq_finalize<<<1, 256, 0, stream>>>(out, counts_f, counts_c, loss_c, loss_f);
}

// Round 4
// 542.034 us; speedup vs baseline: 4.4556x; 2.4524x over previous
//
#include <hip/hip_runtime.h>
#include <math.h>

// Problem dims
#define D 256
#define NEF 8192        // feature codebook
#define NEC 1024        // class codebook

// Output layout (flat float32): loss | quantized[257*64*3*256] | f_perp | c_perp | idx[257*64*3]
#define OUT_QBASE   1
#define OUT_FPERP   12632065
#define OUT_CPERP   12632066
#define OUT_IDXBASE 12632067

// Scratch inside the quantized output region (rewritten by vq_gather later;
// stream-ordered, safe). Float offsets from out+OUT_QBASE:
#define F_SC  0           // feature rescored scores [16384 row][4 part][8]
#define F_IX  524288      // feature candidate codebook idx (int view)
#define C_SC  1048576     // class   rescored scores [64 row][4 part][8]
#define C_IX  1050624
#define EBF_F 1064963     // bf16 feature codebook, row-major (offset chosen so byte addr %16==0)
#define EBF_C 2113539     // bf16 class codebook

// Workspace layout (bytes)
#define WS_CNTF  0        // 8192 int
#define WS_CNTC  32768    // 1024 int
#define WS_LOSSC 36864    // float
#define WS_LOSSF 36868    // float
#define WS_E2F   49152    // 8192 float
#define WS_E2C   81920    // 1024 float

typedef short bf8 __attribute__((ext_vector_type(8)));     // 8 bf16 (4 VGPRs)
typedef float f32x4 __attribute__((ext_vector_type(4)));   // MFMA C/D frag

// float -> bf16 bits, round-to-nearest-even (coarse pass only; rounding mode
// does not affect final selection thanks to exact rescore)
__device__ __forceinline__ unsigned f2bf(float f) {
    union { float f; unsigned u; } v; v.f = f;
    return (v.u + 0x7FFFu + ((v.u >> 16) & 1u)) >> 16;
}

// Lexicographic (score, idx) insert into a sorted 3-slot list.
// Matches jax.lax.top_k stable tie-breaking (equal score -> lower index wins).
__device__ __forceinline__ void insert3(float s, int idx, float* bs, int* bi) {
    bool lt2 = (s < bs[2]) || (s == bs[2] && idx < bi[2]);
    if (lt2) {
        bool lt1 = (s < bs[1]) || (s == bs[1] && idx < bi[1]);
        if (lt1) {
            bs[2] = bs[1]; bi[2] = bi[1];
            bool lt0 = (s < bs[0]) || (s == bs[0] && idx < bi[0]);
            if (lt0) { bs[1] = bs[0]; bi[1] = bi[0]; bs[0] = s; bi[0] = idx; }
            else     { bs[1] = s;     bi[1] = idx; }
        } else       { bs[2] = s;     bi[2] = idx; }
    }
}

// Coarse top-8 insert (score-only compare; any deterministic rule works,
// final selection uses exact rescored scores).
__device__ __forceinline__ void insert8(float s, int idx, float* hs, int* hi) {
    if (s < hs[7]) {
        hs[7] = s; hi[7] = idx;
#pragma unroll
        for (int q = 7; q > 0; --q) {
            if (hs[q] < hs[q - 1]) {
                float ts = hs[q]; hs[q] = hs[q - 1]; hs[q - 1] = ts;
                int   ti = hi[q]; hi[q] = hi[q - 1]; hi[q - 1] = ti;
            }
        }
    }
}

// ---- codebook squared norms (unchanged from R3 -- its e2 values are part of
// the passing selection arithmetic; do not perturb)
__global__ __launch_bounds__(256)
void vq_norms(const float* __restrict__ femb, const float* __restrict__ cemb,
              float* __restrict__ e2f, float* __restrict__ e2c)
{
    int wave = blockIdx.x * 4 + (threadIdx.x >> 6);
    int lane = threadIdx.x & 63;
    const float* src;
    float* dst;
    if (wave < NEF) { src = femb + (size_t)wave * D;         dst = e2f + wave; }
    else            { src = cemb + (size_t)(wave - NEF) * D; dst = e2c + (wave - NEF); }
    float4 v = *(const float4*)(src + lane * 4);
    float s = v.x * v.x + v.y * v.y + v.z * v.z + v.w * v.w;
#pragma unroll
    for (int off = 32; off > 0; off >>= 1) s += __shfl_down(s, off);
    if (lane == 0) *dst = s;
}

// ---- convert codebooks fp32 -> bf16 row-major (one 8-elem group per thread)
__global__ __launch_bounds__(256)
void vq_cvt(const float* __restrict__ femb, const float* __restrict__ cemb,
            unsigned short* __restrict__ ebf_f, unsigned short* __restrict__ ebf_c)
{
    int gid = blockIdx.x * 256 + threadIdx.x;   // 8-element group id
    const float* src; unsigned short* dst;
    if (gid < NEF * 32) { src = femb + (size_t)gid * 8; dst = ebf_f + (size_t)gid * 8; }
    else { int g2 = gid - NEF * 32; src = cemb + (size_t)g2 * 8; dst = ebf_c + (size_t)g2 * 8; }
    float4 a = *(const float4*)src, b = *(const float4*)(src + 4);
    uint4 o;
    o.x = f2bf(a.x) | (f2bf(a.y) << 16);
    o.y = f2bf(a.z) | (f2bf(a.w) << 16);
    o.z = f2bf(b.x) | (f2bf(b.y) << 16);
    o.w = f2bf(b.z) | (f2bf(b.w) << 16);
    *(uint4*)dst = o;
}

// ---- coarse bf16-MFMA pass + in-block top-8 + exact fp32 rescore
// Feature blocks 0..1023: rt=blk>>2 -> rows [64+rt*64,+64); pt=blk&3 -> codes
// [pt*2048,+2048). Class blocks 1024..1027: rows 0..63, codes [p*256,+256).
// Wave w covers rows [w*16,+16) x all 128 embs of each chunk.
// LDS frag layout (16B slots): slot holds 8 bf16 = one MFMA k-group; XOR
// swizzle g' = g ^ ((row>>1)&3) makes staging writes AND frag reads cover all
// 8 bank-groups per 8-lane phase (conflict-free for b128).
__global__ __launch_bounds__(256, 4)
void vq_coarse(const float* __restrict__ features,
               const unsigned short* __restrict__ ebf_f,
               const unsigned short* __restrict__ ebf_c,
               const float* __restrict__ femb, const float* __restrict__ cemb,
               const float* __restrict__ e2f, const float* __restrict__ e2c,
               float* __restrict__ out)
{
    __shared__ uint4 sm[2560];   // 40 KB: X frags [0,2048), E slice [2048,2560)
    const int tid = threadIdx.x;
    const int lane = tid & 63, w = tid >> 6;
    const int l15 = lane & 15, q4 = lane >> 4;
    const int blk = blockIdx.x;
    const bool is_class = blk >= 1024;

    const float* xbase; const unsigned short* ebf; const float* e2p;
    const float* cb; const float* e2full;
    int nchunks, eoff;
    if (is_class) {
        int p = blk - 1024;
        xbase = features; ebf = ebf_c; cb = cemb; e2full = e2c;
        e2p = e2c + p * 256; eoff = p * 256; nchunks = 2;
    } else {
        int rt = blk >> 2, pt = blk & 3;
        xbase = features + (size_t)(64 + rt * 64) * D;
        ebf = ebf_f; cb = femb; e2full = e2f;
        e2p = e2f + pt * 2048; eoff = pt * 2048; nchunks = 16;
    }
    const unsigned short* ebase_ptr = ebf + (size_t)eoff * D;

    // stage X once: fp32 global (fully coalesced: addr = gi*32B) -> bf16 frags
#pragma unroll
    for (int i = 0; i < 8; ++i) {
        int gi = tid + 256 * i;
        int row = gi >> 5, k8 = gi & 31;
        const float* sp = xbase + (size_t)gi * 8;
        float4 a = *(const float4*)sp, b = *(const float4*)(sp + 4);
        uint4 o;
        o.x = f2bf(a.x) | (f2bf(a.y) << 16);
        o.y = f2bf(a.z) | (f2bf(a.w) << 16);
        o.z = f2bf(b.x) | (f2bf(b.y) << 16);
        o.w = f2bf(b.z) | (f2bf(b.w) << 16);
        int s = k8 >> 2, gp = (k8 & 3) ^ ((row >> 1) & 3);
        sm[s * 256 + row * 4 + gp] = o;
    }
    // (X reads are protected by the first E-staging barrier below)

    const int rbase = w * 16;
    const int swz = q4 ^ ((l15 >> 1) & 3);
    const int aoff = (rbase + l15) * 4 + swz;   // X frag slot (+ s*256)
    const int bo = l15 * 4 + swz;               // E frag slot (+ j*64)

    float bs[4][3]; int bi[4][3];
#pragma unroll
    for (int r = 0; r < 4; ++r)
#pragma unroll
        for (int s = 0; s < 3; ++s) { bs[r][s] = 1e30f; bi[r][s] = 0x7FFFFFFF; }

    // E-staging slot decode (s-independent)
    const int e0 = tid >> 2, gp0 = tid & 3;
    const int g0 = gp0 ^ ((e0 >> 1) & 3);
    const int e1 = e0 + 64;
    const int g1 = gp0 ^ ((e1 >> 1) & 3);

    for (int c = 0; c < nchunks; ++c) {
        const unsigned short* ec = ebase_ptr + (size_t)c * 128 * D;
        f32x4 acc[8];
#pragma unroll
        for (int j = 0; j < 8; ++j) acc[j] = (f32x4){0.f, 0.f, 0.f, 0.f};
        for (int s = 0; s < 8; ++s) {
            uint4 v0 = *(const uint4*)(ec + (size_t)e0 * D + s * 32 + g0 * 8);
            uint4 v1 = *(const uint4*)(ec + (size_t)e1 * D + s * 32 + g1 * 8);
            __syncthreads();            // previous slice's reads complete
            sm[2048 + tid] = v0;
            sm[2048 + 256 + tid] = v1;
            __syncthreads();
            bf8 af = *(const bf8*)(sm + s * 256 + aoff);
#pragma unroll
            for (int j = 0; j < 8; ++j) {
                bf8 bv = *(const bf8*)(sm + 2048 + bo + j * 64);
                acc[j] = __builtin_amdgcn_mfma_f32_16x16x32_bf16(af, bv, acc[j], 0, 0, 0);
            }
        }
        // coarse score = ||e||^2 - 2 x.e ; per-lane top-3 per row
#pragma unroll
        for (int j = 0; j < 8; ++j) {
            int el = c * 128 + j * 16 + l15;
            float e2v = e2p[el];
#pragma unroll
            for (int r = 0; r < 4; ++r)
                insert3(fmaf(-2.f, acc[j][r], e2v), el, bs[r], bi[r]);
        }
    }

    // in-block merge: 16 lanes x top-3 -> coarse top-8 per row
    __syncthreads();
    float* msc = (float*)sm;
    int*   mix = (int*)sm + 3072;
    int*   topix = (int*)sm + 6144;   // [64][8]
#pragma unroll
    for (int r = 0; r < 4; ++r) {
        int rowout = rbase + q4 * 4 + r;   // C/D layout: row = quad*4 + reg
#pragma unroll
        for (int s = 0; s < 3; ++s) {
            msc[rowout * 48 + l15 * 3 + s] = bs[r][s];
            mix[rowout * 48 + l15 * 3 + s] = bi[r][s];
        }
    }
    __syncthreads();
    if (tid < 64) {
        float hs[8]; int hi[8];
#pragma unroll
        for (int q = 0; q < 8; ++q) { hs[q] = 1e30f; hi[q] = 0x7FFFFFFF; }
        for (int t = 0; t < 48; ++t)
            insert8(msc[tid * 48 + t], mix[tid * 48 + t], hs, hi);
#pragma unroll
        for (int q = 0; q < 8; ++q) topix[tid * 8 + q] = hi[q];
    }
    __syncthreads();

    // exact fp32 rescore (bit-identical chain to the R3 kernel: single acc,
    // ascending k, score = fmaf(-2, acc, e2)) -> partition candidate lists
    float* base = out + OUT_QBASE;
    int* ibase = (int*)base;
    for (int it = 0; it < 2; ++it) {
        int row = it * 32 + (tid >> 3), cand = tid & 7;
        int el = topix[row * 8 + cand];
        int eg = eoff + el;
        const float* xp = xbase + (size_t)row * D;
        const float* ep = cb + (size_t)eg * D;
        float acc = 0.f;
#pragma unroll 4
        for (int qq = 0; qq < 64; ++qq) {
            float4 x = *(const float4*)(xp + qq * 4);
            float4 e = *(const float4*)(ep + qq * 4);
            acc = fmaf(x.x, e.x, acc);
            acc = fmaf(x.y, e.y, acc);
            acc = fmaf(x.z, e.z, acc);
            acc = fmaf(x.w, e.w, acc);
        }
        float sc = fmaf(-2.f, acc, e2full[eg]);
        if (is_class) {
            int p = blk - 1024;
            base [C_SC + ((size_t)row * 4 + p) * 8 + cand] = sc;
            ibase[C_IX + ((size_t)row * 4 + p) * 8 + cand] = eg;
        } else {
            int rt = blk >> 2, pt = blk & 3;
            size_t gr = (size_t)rt * 64 + row;
            base [F_SC + (gr * 4 + pt) * 8 + cand] = sc;
            ibase[F_IX + (gr * 4 + pt) * 8 + cand] = eg;
        }
    }
}

// ---- final merge across the 4 partitions: exact top-3, indices + counts
__global__ __launch_bounds__(256)
void vq_fmerge(float* __restrict__ out, int* __restrict__ counts_f,
               int* __restrict__ counts_c)
{
    const int tid = threadIdx.x, blk = blockIdx.x;
    const float* base = out + OUT_QBASE;
    const int* ibase = (const int*)base;
    if (blk < 64) {
        size_t r = (size_t)blk * 256 + tid;   // feature row
        float fb[3] = {1e30f, 1e30f, 1e30f};
        int   fi[3] = {0x7FFFFFFF, 0x7FFFFFFF, 0x7FFFFFFF};
        for (int t = 0; t < 32; ++t)
            insert3(base[F_SC + r * 32 + t], ibase[F_IX + r * 32 + t], fb, fi);
#pragma unroll
        for (int s = 0; s < 3; ++s) {
            out[OUT_IDXBASE + (64 + r) * 3 + s] = (float)(fi[s] + NEC);
            atomicAdd(&counts_f[fi[s]], 1);
        }
    } else if (tid < 64) {
        size_t r = (size_t)tid;               // class row
        float fb[3] = {1e30f, 1e30f, 1e30f};
        int   fi[3] = {0x7FFFFFFF, 0x7FFFFFFF, 0x7FFFFFFF};
        for (int t = 0; t < 32; ++t)
            insert3(base[C_SC + r * 32 + t], ibase[C_IX + r * 32 + t], fb, fi);
#pragma unroll
        for (int s = 0; s < 3; ++s) {
            out[OUT_IDXBASE + r * 3 + s] = (float)fi[s];
            atomicAdd(&counts_c[fi[s]], 1);
        }
    }
}

// ---- gather emb[idx] -> quantized output, accumulate losses (unchanged R3)
__global__ __launch_bounds__(256)
void vq_gather(const float* __restrict__ features, const float* __restrict__ femb,
               const float* __restrict__ cemb, float* __restrict__ out,
               float* __restrict__ loss_c, float* __restrict__ loss_f)
{
    const int tid = threadIdx.x;
    const int s = blockIdx.x * 4 + (tid >> 6);   // slot in [0, 49344)
    const int lane = tid & 63;
    const int row = s / 3;                        // global token-row 0..16447
    const int idx = (int)out[OUT_IDXBASE + s];
    const float* xp = features + (size_t)row * D;
    const float* ep = (row < 64) ? cemb + (size_t)idx * D
                                 : femb + (size_t)(idx - NEC) * D;
    const int koff = lane * 4;
    float4 e = *(const float4*)(ep + koff);
    float4 x = *(const float4*)(xp + koff);
    float dx = e.x - x.x, dy = e.y - x.y, dz = e.z - x.z, dw = e.w - x.w;
    float lsum = dx * dx + dy * dy + dz * dz + dw * dw;
    size_t ob = OUT_QBASE + (size_t)s * D + koff;   // base misaligned by 1 -> b32 stores
    out[ob + 0] = e.x; out[ob + 1] = e.y; out[ob + 2] = e.z; out[ob + 3] = e.w;
#pragma unroll
    for (int off = 32; off > 0; off >>= 1) lsum += __shfl_down(lsum, off);
    __shared__ float wl[4];
    if (lane == 0) wl[tid >> 6] = lsum;
    __syncthreads();
    if (tid == 0) {
        float t = wl[0] + wl[1] + wl[2] + wl[3];
        atomicAdd(blockIdx.x < 48 ? loss_c : loss_f, t);
    }
}

// ---- scalar epilogue: perplexities + loss (unchanged R3)
__global__ __launch_bounds__(256)
void vq_finalize(float* __restrict__ out, const int* __restrict__ counts_f,
                 const int* __restrict__ counts_c, const float* __restrict__ loss_c,
                 const float* __restrict__ loss_f)
{
    __shared__ double dred[256];
    const int tid = threadIdx.x;
    double acc = 0.0;
    for (int i = tid; i < NEF; i += 256) {
        double p = (double)counts_f[i] / 16384.0;
        acc += p * log(p + 1e-10);
    }
    dred[tid] = acc;
    __syncthreads();
    for (int st = 128; st > 0; st >>= 1) {
        if (tid < st) dred[tid] += dred[tid + st];
        __syncthreads();
    }
    double ent_f = -dred[0];
    __syncthreads();
    acc = 0.0;
    for (int i = tid; i < NEC; i += 256) {
        double p = (double)counts_c[i] / 64.0;
        acc += p * log(p + 1e-10);
    }
    dred[tid] = acc;
    __syncthreads();
    for (int st = 128; st > 0; st >>= 1) {
        if (tid < st) dred[tid] += dred[tid + st];
        __syncthreads();
    }
    double ent_c = -dred[0];
    if (tid == 0) {
        out[OUT_FPERP] = (float)exp(ent_f);
        out[OUT_CPERP] = (float)exp(ent_c);
        out[0] = 1.25f * (*loss_c / 49152.0f + *loss_f / 12582912.0f);
    }
}

extern "C" void kernel_launch(void* const* d_in, const int* in_sizes, int n_in,
                              void* d_out, int out_size, void* d_ws, size_t ws_size,
                              hipStream_t stream)
{
    const float* features = (const float*)d_in[0];  // [257*64, 256]
    const float* cemb     = (const float*)d_in[1];  // [1024, 256]
    const float* femb     = (const float*)d_in[2];  // [8192, 256]
    float* out = (float*)d_out;
    char*  ws  = (char*)d_ws;

    int*   counts_f = (int*)  (ws + WS_CNTF);
    int*   counts_c = (int*)  (ws + WS_CNTC);
    float* loss_c   = (float*)(ws + WS_LOSSC);
    float* loss_f   = (float*)(ws + WS_LOSSF);
    float* e2f      = (float*)(ws + WS_E2F);
    float* e2c      = (float*)(ws + WS_E2C);

    unsigned short* ebf_f = (unsigned short*)(out + OUT_QBASE + EBF_F);
    unsigned short* ebf_c = (unsigned short*)(out + OUT_QBASE + EBF_C);

    // zero counts + loss accumulators (ws is poisoned 0xAA before every call)
    hipMemsetAsync(d_ws, 0, 36872, stream);
    vq_norms<<<2304, 256, 0, stream>>>(femb, cemb, e2f, e2c);
    vq_cvt<<<1152, 256, 0, stream>>>(femb, cemb, ebf_f, ebf_c);
    vq_coarse<<<1028, 256, 0, stream>>>(features, ebf_f, ebf_c, femb, cemb,
                                        e2f, e2c, out);
    vq_fmerge<<<65, 256, 0, stream>>>(out, counts_f, counts_c);
    vq_gather<<<12336, 256, 0, stream>>>(features, femb, cemb, out, loss_c, loss_f);
    vq_finalize<<<1, 256, 0, stream>>>(out, counts_f, counts_c, loss_c, loss_f);
}

// Round 5
// 446.874 us; speedup vs baseline: 5.4044x; 1.2129x over previous
//
#include <hip/hip_runtime.h>
#include <math.h>

// Problem dims
#define D 256
#define NEF 8192        // feature codebook
#define NEC 1024        // class codebook

// Output layout (flat float32): loss | quantized[257*64*3*256] | f_perp | c_perp | idx[257*64*3]
#define OUT_QBASE   1
#define OUT_FPERP   12632065
#define OUT_CPERP   12632066
#define OUT_IDXBASE 12632067

// Scratch inside the quantized output region (rewritten by vq_gather later;
// fmerge completes before gather launches -> no overlap race). Float offsets:
#define F_SC  0           // feature rescored scores [16384 row][4 part][8]
#define F_IX  524288      // feature candidate codebook idx (int view)
#define C_SC  1048576     // class   rescored scores [64 row][4 part][8]
#define C_IX  1050624
#define EBF_F 1064963     // bf16 feature codebook, row-major (byte addr %16==0)
#define EBF_C 2113539     // bf16 class codebook

// Workspace layout (bytes)
#define WS_CNTF  0        // 8192 int
#define WS_CNTC  32768    // 1024 int
#define WS_LOSS  36864    // float[2]: loss_c, loss_f
#define WS_E2F   49152    // 8192 float
#define WS_E2C   81920    // 1024 float

typedef short bf8 __attribute__((ext_vector_type(8)));     // 8 bf16 (4 VGPRs)
typedef float f32x4 __attribute__((ext_vector_type(4)));   // MFMA C/D frag

// float -> bf16 bits, round-to-nearest-even (coarse pass only)
__device__ __forceinline__ unsigned f2bf(float f) {
    union { float f; unsigned u; } v; v.f = f;
    return (v.u + 0x7FFFu + ((v.u >> 16) & 1u)) >> 16;
}

// Lexicographic (score, idx) insert — EXACT-path only (fmerge). Matches
// jax.lax.top_k stable tie-breaking.
__device__ __forceinline__ void insert3(float s, int idx, float* bs, int* bi) {
    bool lt2 = (s < bs[2]) || (s == bs[2] && idx < bi[2]);
    if (lt2) {
        bool lt1 = (s < bs[1]) || (s == bs[1] && idx < bi[1]);
        if (lt1) {
            bs[2] = bs[1]; bi[2] = bi[1];
            bool lt0 = (s < bs[0]) || (s == bs[0] && idx < bi[0]);
            if (lt0) { bs[1] = bs[0]; bi[1] = bi[0]; bs[0] = s; bi[0] = idx; }
            else     { bs[1] = s;     bi[1] = idx; }
        } else       { bs[2] = s;     bi[2] = idx; }
    }
}

// Coarse top-3 insert, score-only (tie order immaterial: exact rescore decides)
__device__ __forceinline__ void insert3c(float s, int idx, float* bs, int* bi) {
    if (s < bs[2]) {
        bs[2] = s; bi[2] = idx;
        if (bs[2] < bs[1]) {
            float t = bs[1]; bs[1] = bs[2]; bs[2] = t;
            int   u = bi[1]; bi[1] = bi[2]; bi[2] = u;
            if (bs[1] < bs[0]) {
                t = bs[0]; bs[0] = bs[1]; bs[1] = t;
                u = bi[0]; bi[0] = bi[1]; bi[1] = u;
            }
        }
    }
}

// Coarse top-8 insert (score-only)
__device__ __forceinline__ void insert8(float s, int idx, float* hs, int* hi) {
    if (s < hs[7]) {
        hs[7] = s; hi[7] = idx;
#pragma unroll
        for (int q = 7; q > 0; --q) {
            if (hs[q] < hs[q - 1]) {
                float ts = hs[q]; hs[q] = hs[q - 1]; hs[q - 1] = ts;
                int   ti = hi[q]; hi[q] = hi[q - 1]; hi[q - 1] = ti;
            }
        }
    }
}

// ---- fused: codebook norms (same shuffle-tree as R4) + fp32->bf16 convert +
// workspace zeroing (replaces hipMemsetAsync + vq_norms + vq_cvt)
__global__ __launch_bounds__(256)
void vq_prep(const float* __restrict__ femb, const float* __restrict__ cemb,
             unsigned short* __restrict__ ebf_f, unsigned short* __restrict__ ebf_c,
             float* __restrict__ e2f, float* __restrict__ e2c,
             int* __restrict__ counts_f, int* __restrict__ counts_c,
             float* __restrict__ loss)
{
    int zid = blockIdx.x * 256 + threadIdx.x;
    if (zid < 8192)      counts_f[zid] = 0;
    else if (zid < 9216) counts_c[zid - 8192] = 0;
    else if (zid < 9218) loss[zid - 9216] = 0.f;

    int wave = blockIdx.x * 4 + (threadIdx.x >> 6);
    int lane = threadIdx.x & 63;
    const float* src; unsigned short* dst; float* ndst;
    if (wave < NEF) { src = femb + (size_t)wave * D; dst = ebf_f + (size_t)wave * D; ndst = e2f + wave; }
    else { int w2 = wave - NEF; src = cemb + (size_t)w2 * D; dst = ebf_c + (size_t)w2 * D; ndst = e2c + w2; }
    float4 v = *(const float4*)(src + lane * 4);
    uint2 o;
    o.x = f2bf(v.x) | (f2bf(v.y) << 16);
    o.y = f2bf(v.z) | (f2bf(v.w) << 16);
    *(uint2*)(dst + lane * 4) = o;
    float s = v.x * v.x + v.y * v.y + v.z * v.z + v.w * v.w;
#pragma unroll
    for (int off = 32; off > 0; off >>= 1) s += __shfl_down(s, off);
    if (lane == 0) *ndst = s;
}

// ---- coarse bf16-MFMA pass, R5 structure:
// 32x64 wave tiles (wave grid 2x2 over the 64-row x 128-emb chunk), E slices
// double-buffered with ONE barrier per k32-slice, global prefetch issued
// before the slice's MFMAs. Per wave per slice: 2 af + 4 ef reads + 2 writes
// feed 8 MFMAs (vs R4's 9 reads + 2 writes per 8 MFMAs, 2 barriers/slice).
__global__ __launch_bounds__(256, 3)
void vq_coarse(const float* __restrict__ features,
               const unsigned short* __restrict__ ebf_f,
               const unsigned short* __restrict__ ebf_c,
               const float* __restrict__ femb, const float* __restrict__ cemb,
               const float* __restrict__ e2f, const float* __restrict__ e2c,
               float* __restrict__ out)
{
    __shared__ uint4 sm[3200];   // 50 KB: X [0,2048), Ebuf0 [2048,2560), Ebuf1 [2560,3072)
    const int tid = threadIdx.x, lane = tid & 63, w = tid >> 6;
    const int l15 = lane & 15, q4 = lane >> 4;
    const int wr = w & 1, we = w >> 1;        // row-half, emb-half
    const int blk = blockIdx.x;
    const bool is_class = blk >= 1024;

    const float* xbase; const unsigned short* ebf; const float* e2p;
    const float* cb; const float* e2full;
    int nchunks, eoff;
    if (is_class) {
        int p = blk - 1024;
        xbase = features; ebf = ebf_c; cb = cemb; e2full = e2c;
        e2p = e2c + p * 256; eoff = p * 256; nchunks = 2;
    } else {
        int rt = blk >> 2, pt = blk & 3;
        xbase = features + (size_t)(64 + rt * 64) * D;
        ebf = ebf_f; cb = femb; e2full = e2f;
        e2p = e2f + pt * 2048; eoff = pt * 2048; nchunks = 16;
    }
    const unsigned short* ebase = ebf + (size_t)eoff * D;

    // stage X once: fp32 global -> bf16 frags (R4 pattern, verified)
#pragma unroll
    for (int i = 0; i < 8; ++i) {
        int gi = tid + 256 * i;
        int row = gi >> 5, k8 = gi & 31;
        const float* sp = xbase + (size_t)gi * 8;
        float4 a = *(const float4*)sp, b = *(const float4*)(sp + 4);
        uint4 o;
        o.x = f2bf(a.x) | (f2bf(a.y) << 16);
        o.y = f2bf(a.z) | (f2bf(a.w) << 16);
        o.z = f2bf(b.x) | (f2bf(b.y) << 16);
        o.w = f2bf(b.z) | (f2bf(b.w) << 16);
        int s = k8 >> 2, gp = (k8 & 3) ^ ((row >> 1) & 3);
        sm[s * 256 + row * 4 + gp] = o;
    }

    // E-staging lane decode (R4 pattern: swizzled-group load, linear store)
    const int e0 = tid >> 2, gp0 = tid & 3;
    const int g0 = gp0 ^ ((e0 >> 1) & 3);
    const int e1 = e0 + 64;
    const int g1 = gp0 ^ ((e1 >> 1) & 3);

    // prefetch slice 0 (chunk 0, s 0) while X staging drains
    uint4 p0 = *(const uint4*)(ebase + (size_t)e0 * D + g0 * 8);
    uint4 p1 = *(const uint4*)(ebase + (size_t)e1 * D + g1 * 8);
    __syncthreads();                 // X visible
    sm[2048 + tid] = p0;
    sm[2048 + 256 + tid] = p1;
    __syncthreads();                 // E slice 0 visible

    const int swz = q4 ^ ((l15 >> 1) & 3);
    const int a0 = (wr * 32 + l15) * 4 + swz;    // A frag slot (+ s*256; +64 for 2nd row tile)
    const int bq = we * 256 + l15 * 4 + swz;     // B frag slot (+ j*64)

    float bsc[2][4][3]; int bix[2][4][3];        // per-lane top-3 for 8 rows
#pragma unroll
    for (int i = 0; i < 2; ++i)
#pragma unroll
        for (int r = 0; r < 4; ++r)
#pragma unroll
            for (int s3 = 0; s3 < 3; ++s3) { bsc[i][r][s3] = 1e30f; bix[i][r][s3] = 0x7FFFFFFF; }

    f32x4 acc[2][4];
#pragma unroll
    for (int i = 0; i < 2; ++i)
#pragma unroll
        for (int j = 0; j < 4; ++j) acc[i][j] = (f32x4){0.f, 0.f, 0.f, 0.f};

    const int nsl = nchunks * 8;
    for (int sf = 0; sf < nsl; ++sf) {
        const int s = sf & 7;
        const bool more = (sf + 1 < nsl);
        uint4 q0, q1;
        if (more) {   // issue next-slice global loads before this slice's MFMAs
            const unsigned short* en = ebase + (size_t)((sf + 1) >> 3) * 128 * D
                                             + ((sf + 1) & 7) * 32;
            q0 = *(const uint4*)(en + (size_t)e0 * D + g0 * 8);
            q1 = *(const uint4*)(en + (size_t)e1 * D + g1 * 8);
        }
        const uint4* xb = sm + s * 256;
        const uint4* eb = sm + 2048 + (sf & 1) * 512;
        bf8 af0 = *(const bf8*)(xb + a0);
        bf8 af1 = *(const bf8*)(xb + a0 + 64);
#pragma unroll
        for (int j = 0; j < 4; ++j) {
            bf8 bv = *(const bf8*)(eb + bq + j * 64);
            acc[0][j] = __builtin_amdgcn_mfma_f32_16x16x32_bf16(af0, bv, acc[0][j], 0, 0, 0);
            acc[1][j] = __builtin_amdgcn_mfma_f32_16x16x32_bf16(af1, bv, acc[1][j], 0, 0, 0);
        }
        if (s == 7) {   // chunk done: fold scores into per-lane top-3, reset acc
            const int c = sf >> 3;
#pragma unroll
            for (int j = 0; j < 4; ++j) {
                const int el = c * 128 + we * 64 + j * 16 + l15;
                const float e2v = e2p[el];
#pragma unroll
                for (int i = 0; i < 2; ++i)
#pragma unroll
                    for (int r = 0; r < 4; ++r)
                        insert3c(fmaf(-2.f, acc[i][j][r], e2v), el, bsc[i][r], bix[i][r]);
            }
#pragma unroll
            for (int i = 0; i < 2; ++i)
#pragma unroll
                for (int j = 0; j < 4; ++j) acc[i][j] = (f32x4){0.f, 0.f, 0.f, 0.f};
        }
        if (more) {   // write prefetched slice into the other buffer
            uint4* ebn = sm + 2048 + ((sf + 1) & 1) * 512;
            ebn[tid] = q0;
            ebn[tid + 256] = q1;
        }
        __syncthreads();   // writes visible; all reads of overwritten buf done
    }

    // block merge: 64 rows x (2 waves x 16 lanes x top3) -> coarse top-8/row
    float* msc = (float*)sm;          // [64][32][3]
    int*   mix = (int*)sm + 6144;
    int*   topix = (int*)sm + 12288;  // [64][8]
#pragma unroll
    for (int i = 0; i < 2; ++i)
#pragma unroll
        for (int r = 0; r < 4; ++r) {
            int row = wr * 32 + i * 16 + q4 * 4 + r;   // C layout: row = quad*4 + reg
            int col = we * 16 + l15;
#pragma unroll
            for (int s3 = 0; s3 < 3; ++s3) {
                msc[(row * 32 + col) * 3 + s3] = bsc[i][r][s3];
                mix[(row * 32 + col) * 3 + s3] = bix[i][r][s3];
            }
        }
    __syncthreads();
    if (tid < 64) {
        float hs[8]; int hi[8];
#pragma unroll
        for (int q = 0; q < 8; ++q) { hs[q] = 1e30f; hi[q] = 0x7FFFFFFF; }
        for (int t = 0; t < 96; ++t)
            insert8(msc[tid * 96 + t], mix[tid * 96 + t], hs, hi);
#pragma unroll
        for (int q = 0; q < 8; ++q) topix[tid * 8 + q] = hi[q];
    }
    __syncthreads();

    // exact fp32 rescore (bit-identical chain to R3/R4: single acc, ascending
    // k, score = fmaf(-2, acc, e2)) -> partition candidate lists
    float* base = out + OUT_QBASE;
    int* ibase = (int*)base;
    for (int it = 0; it < 2; ++it) {
        int row = it * 32 + (tid >> 3), cand = tid & 7;
        int el = topix[row * 8 + cand];
        int eg = eoff + el;
        const float* xp = xbase + (size_t)row * D;
        const float* ep = cb + (size_t)eg * D;
        float acc1 = 0.f;
#pragma unroll 4
        for (int qq = 0; qq < 64; ++qq) {
            float4 x = *(const float4*)(xp + qq * 4);
            float4 e = *(const float4*)(ep + qq * 4);
            acc1 = fmaf(x.x, e.x, acc1);
            acc1 = fmaf(x.y, e.y, acc1);
            acc1 = fmaf(x.z, e.z, acc1);
            acc1 = fmaf(x.w, e.w, acc1);
        }
        float sc = fmaf(-2.f, acc1, e2full[eg]);
        if (is_class) {
            int p = blk - 1024;
            base [C_SC + ((size_t)row * 4 + p) * 8 + cand] = sc;
            ibase[C_IX + ((size_t)row * 4 + p) * 8 + cand] = eg;
        } else {
            int rt = blk >> 2, pt = blk & 3;
            size_t gr = (size_t)rt * 64 + row;
            base [F_SC + (gr * 4 + pt) * 8 + cand] = sc;
            ibase[F_IX + (gr * 4 + pt) * 8 + cand] = eg;
        }
    }
}

// ---- final merge across the 4 partitions: exact top-3, indices + counts
// (separate kernel: must complete before vq_gather overwrites scratch)
__global__ __launch_bounds__(256)
void vq_fmerge(float* __restrict__ out, int* __restrict__ counts_f,
               int* __restrict__ counts_c)
{
    const int tid = threadIdx.x, blk = blockIdx.x;
    const float* base = out + OUT_QBASE;
    const int* ibase = (const int*)base;
    if (blk < 64) {
        size_t r = (size_t)blk * 256 + tid;   // feature row
        float fb[3] = {1e30f, 1e30f, 1e30f};
        int   fi[3] = {0x7FFFFFFF, 0x7FFFFFFF, 0x7FFFFFFF};
        for (int t = 0; t < 32; ++t)
            insert3(base[F_SC + r * 32 + t], ibase[F_IX + r * 32 + t], fb, fi);
#pragma unroll
        for (int s = 0; s < 3; ++s) {
            out[OUT_IDXBASE + (64 + r) * 3 + s] = (float)(fi[s] + NEC);
            atomicAdd(&counts_f[fi[s]], 1);
        }
    } else if (tid < 64) {
        size_t r = (size_t)tid;               // class row
        float fb[3] = {1e30f, 1e30f, 1e30f};
        int   fi[3] = {0x7FFFFFFF, 0x7FFFFFFF, 0x7FFFFFFF};
        for (int t = 0; t < 32; ++t)
            insert3(base[C_SC + r * 32 + t], ibase[C_IX + r * 32 + t], fb, fi);
#pragma unroll
        for (int s = 0; s < 3; ++s) {
            out[OUT_IDXBASE + r * 3 + s] = (float)fi[s];
            atomicAdd(&counts_c[fi[s]], 1);
        }
    }
}

// ---- gather emb[idx] -> quantized output + losses. One block per 64 rows
// (257 blocks; block 0 = class rows). Indices read back from OUT_IDXBASE.
__global__ __launch_bounds__(256)
void vq_gather(const float* __restrict__ features, const float* __restrict__ femb,
               const float* __restrict__ cemb, float* __restrict__ out,
               float* __restrict__ loss)
{
    __shared__ int sidx[192];
    __shared__ float red[256];
    const int tid = threadIdx.x, b = blockIdx.x;
    if (tid < 192) sidx[tid] = (int)out[OUT_IDXBASE + (size_t)b * 192 + tid];
    __syncthreads();
    const float* xb = features + (size_t)b * 64 * D;
    float lsum = 0.f;
    const int g = tid >> 4, l16 = tid & 15;
    for (int rs = g; rs < 192; rs += 16) {
        int rloc = rs / 3, slot = rs - rloc * 3;
        int idx = sidx[rs];
        const float* ep = (b == 0) ? cemb + (size_t)idx * D
                                   : femb + (size_t)(idx - NEC) * D;
        const float* xp = xb + (size_t)rloc * D;
        size_t ob = OUT_QBASE + (((size_t)b * 64 + rloc) * 3 + slot) * D;
#pragma unroll
        for (int qq = 0; qq < 4; ++qq) {
            int kk = (qq * 16 + l16) * 4;
            float4 e = *(const float4*)(ep + kk);
            float4 x = *(const float4*)(xp + kk);
            float dx = e.x - x.x, dy = e.y - x.y, dz = e.z - x.z, dw = e.w - x.w;
            lsum += dx * dx + dy * dy + dz * dz + dw * dw;
            // scalar stores: quantized region starts at out+1 (4B-aligned only)
            out[ob + kk + 0] = e.x; out[ob + kk + 1] = e.y;
            out[ob + kk + 2] = e.z; out[ob + kk + 3] = e.w;
        }
    }
    red[tid] = lsum;
    __syncthreads();
    for (int st = 128; st > 0; st >>= 1) {
        if (tid < st) red[tid] += red[tid + st];
        __syncthreads();
    }
    if (tid == 0) atomicAdd(b == 0 ? loss + 0 : loss + 1, red[0]);
}

// ---- scalar epilogue: perplexities + loss
__global__ __launch_bounds__(256)
void vq_finalize(float* __restrict__ out, const int* __restrict__ counts_f,
                 const int* __restrict__ counts_c, const float* __restrict__ loss)
{
    __shared__ double dred[256];
    const int tid = threadIdx.x;
    double acc = 0.0;
    for (int i = tid; i < NEF; i += 256) {
        double p = (double)counts_f[i] / 16384.0;
        acc += p * log(p + 1e-10);
    }
    dred[tid] = acc;
    __syncthreads();
    for (int st = 128; st > 0; st >>= 1) {
        if (tid < st) dred[tid] += dred[tid + st];
        __syncthreads();
    }
    double ent_f = -dred[0];
    __syncthreads();
    acc = 0.0;
    for (int i = tid; i < NEC; i += 256) {
        double p = (double)counts_c[i] / 64.0;
        acc += p * log(p + 1e-10);
    }
    dred[tid] = acc;
    __syncthreads();
    for (int st = 128; st > 0; st >>= 1) {
        if (tid < st) dred[tid] += dred[tid + st];
        __syncthreads();
    }
    double ent_c = -dred[0];
    if (tid == 0) {
        out[OUT_FPERP] = (float)exp(ent_f);
        out[OUT_CPERP] = (float)exp(ent_c);
        out[0] = 1.25f * (loss[0] / 49152.0f + loss[1] / 12582912.0f);
    }
}

extern "C" void kernel_launch(void* const* d_in, const int* in_sizes, int n_in,
                              void* d_out, int out_size, void* d_ws, size_t ws_size,
                              hipStream_t stream)
{
    const float* features = (const float*)d_in[0];  // [257*64, 256]
    const float* cemb     = (const float*)d_in[1];  // [1024, 256]
    const float* femb     = (const float*)d_in[2];  // [8192, 256]
    float* out = (float*)d_out;
    char*  ws  = (char*)d_ws;

    int*   counts_f = (int*)  (ws + WS_CNTF);
    int*   counts_c = (int*)  (ws + WS_CNTC);
    float* loss     = (float*)(ws + WS_LOSS);
    float* e2f      = (float*)(ws + WS_E2F);
    float* e2c      = (float*)(ws + WS_E2C);

    unsigned short* ebf_f = (unsigned short*)(out + OUT_QBASE + EBF_F);
    unsigned short* ebf_c = (unsigned short*)(out + OUT_QBASE + EBF_C);

    vq_prep<<<2304, 256, 0, stream>>>(femb, cemb, ebf_f, ebf_c, e2f, e2c,
                                      counts_f, counts_c, loss);
    vq_coarse<<<1028, 256, 0, stream>>>(features, ebf_f, ebf_c, femb, cemb,
                                        e2f, e2c, out);
    vq_fmerge<<<65, 256, 0, stream>>>(out, counts_f, counts_c);
    vq_gather<<<257, 256, 0, stream>>>(features, femb, cemb, out, loss);
    vq_finalize<<<1, 256, 0, stream>>>(out, counts_f, counts_c, loss);
}